// Round 1
// baseline (3717.341 us; speedup 1.0000x reference)
//
#include <hip/hip_runtime.h>

#define NB   8
#define NP   8192
#define NS   2048
#define NK   16
#define DIN  64
#define DOUT 128
#define BN_EPS 1e-5f

// ---------------- K0: fold BN into weights, transpose to [k][o] ----------------
__global__ void fold_weights_kernel(const float* __restrict__ W, const float* __restrict__ bias,
                                    const float* __restrict__ gamma, const float* __restrict__ beta,
                                    const float* __restrict__ rmean, const float* __restrict__ rvar,
                                    float* __restrict__ Wt, float* __restrict__ Cb)
{
    int i = blockIdx.x * 256 + threadIdx.x;
    if (i < DIN * DOUT) {
        int o = i & (DOUT - 1);
        int k = i >> 7;
        float sc = gamma[o] * rsqrtf(rvar[o] + BN_EPS);
        Wt[i] = W[o * DIN + k] * sc;            // Wt[k*128 + o]
        if (i < DOUT) {
            Cb[i] = (bias[i] - rmean[i]) * sc + beta[i];
        }
    }
}

// ---------------- K1: farthest point sampling (1 block per batch) ----------------
#define FT 256
#define FP (NP / FT)   // 32 points per thread

__global__ __launch_bounds__(FT, 1)
void fps_kernel(const float* __restrict__ coords, float* __restrict__ out_coords)
{
#pragma clang fp contract(off)
    __shared__ float sx[NP], sy[NP], sz[NP];
    __shared__ float rv[2][FT / 64];
    __shared__ int   ri[2][FT / 64];

    const int b = blockIdx.x, t = threadIdx.x;
    const float* cb = coords + (size_t)b * NP * 3;

    for (int i = t; i < NP; i += FT) {
        sx[i] = cb[i * 3 + 0];
        sy[i] = cb[i * 3 + 1];
        sz[i] = cb[i * 3 + 2];
    }
    __syncthreads();

    float px[FP], py[FP], pz[FP], dist[FP];
#pragma unroll
    for (int k = 0; k < FP; ++k) {
        int i = t + k * FT;
        px[k] = sx[i]; py[k] = sy[i]; pz[k] = sz[i];
        dist[k] = 1e10f;
    }

    const int wave = t >> 6, lane = t & 63;
    int cur = 0;
    float* ocb = out_coords + (size_t)b * NS * 3;

    for (int s = 0; s < NS; ++s) {
        float cx = sx[cur], cy = sy[cur], cz = sz[cur];
        if (t == 0) {
            ocb[s * 3 + 0] = cx; ocb[s * 3 + 1] = cy; ocb[s * 3 + 2] = cz;
        }
        // update min-dist + local argmax (first-occurrence == smallest global idx)
        float m = -1.0f; int li = 0;
#pragma unroll
        for (int k = 0; k < FP; ++k) {
            float dx = px[k] - cx, dy = py[k] - cy, dz = pz[k] - cz;
            float d = ((dx * dx) + (dy * dy)) + (dz * dz);
            float nd = dist[k] < d ? dist[k] : d;
            dist[k] = nd;
            if (nd > m) { m = nd; li = t + k * FT; }
        }
        // wave reduce: max value, tie -> min index
#pragma unroll
        for (int off = 32; off >= 1; off >>= 1) {
            float om = __shfl_xor(m, off);
            int   oi = __shfl_xor(li, off);
            if (om > m || (om == m && oi < li)) { m = om; li = oi; }
        }
        int pb = s & 1;
        if (lane == 0) { rv[pb][wave] = m; ri[pb][wave] = li; }
        __syncthreads();
        float bm = rv[pb][0]; int bi = ri[pb][0];
#pragma unroll
        for (int w = 1; w < FT / 64; ++w) {
            float vm = rv[pb][w]; int vi = ri[pb][w];
            if (vm > bm || (vm == bm && vi < bi)) { bm = vm; bi = vi; }
        }
        cur = bi;
    }
}

// ---------------- K2: pointwise MLP (conv1x1 + folded BN + relu) ----------------
__global__ __launch_bounds__(256)
void mlp_kernel(const float* __restrict__ feat, const float* __restrict__ Wt,
                const float* __restrict__ Cb, float* __restrict__ h)
{
    __shared__ float sf[2][DIN];
    const int t = threadIdx.x;
    const int o = t & (DOUT - 1);
    const int r2 = t >> 7;
    const size_t row0 = (size_t)blockIdx.x * 2;

    if (t < 2 * DIN) sf[t >> 6][t & 63] = feat[row0 * DIN + t];
    __syncthreads();

    float acc = Cb[o];
    const float4* f4 = (const float4*)sf[r2];
#pragma unroll
    for (int k4 = 0; k4 < DIN / 4; ++k4) {
        float4 f = f4[k4];
        acc = fmaf(f.x, Wt[(k4 * 4 + 0) * DOUT + o], acc);
        acc = fmaf(f.y, Wt[(k4 * 4 + 1) * DOUT + o], acc);
        acc = fmaf(f.z, Wt[(k4 * 4 + 2) * DOUT + o], acc);
        acc = fmaf(f.w, Wt[(k4 * 4 + 3) * DOUT + o], acc);
    }
    h[(row0 + r2) * DOUT + o] = fmaxf(acc, 0.0f);
}

// ---------------- K3: exact KNN (block per query, radix-cut + extraction) ----------------
#define KT 256
#define KJ (NP / KT)   // 32
#define NBINS 256
#define MAXC 512

__global__ __launch_bounds__(KT, 1)
void knn_kernel(const float* __restrict__ coords, const float* __restrict__ qc,
                int* __restrict__ knn)
{
#pragma clang fp contract(off)
    __shared__ float sdist[NP];
    __shared__ unsigned hist[NBINS];
    __shared__ float cd[MAXC];
    __shared__ int   ci[MAXC];
    __shared__ unsigned ccnt;
    __shared__ int s_cut;

    const int q = blockIdx.x;
    const int b = q >> 11;
    const int t = threadIdx.x;
    const float* cb = coords + (size_t)b * NP * 3;
    const float qx = qc[(size_t)q * 3 + 0];
    const float qy = qc[(size_t)q * 3 + 1];
    const float qz = qc[(size_t)q * 3 + 2];

    for (int i = t; i < NBINS; i += KT) hist[i] = 0;
    if (t == 0) ccnt = 0;
    __syncthreads();

    for (int j = 0; j < KJ; ++j) {
        int i = t + j * KT;
        float dx = cb[i * 3 + 0] - qx, dy = cb[i * 3 + 1] - qy, dz = cb[i * 3 + 2] - qz;
        float d = ((dx * dx) + (dy * dy)) + (dz * dz);
        sdist[i] = d;
        atomicAdd(&hist[__float_as_uint(d) >> 23], 1u);   // positive floats: exponent bins
    }
    __syncthreads();

    // one wave finds the cut bin (cum count crosses NK)
    if (t < 64) {
        unsigned c0 = hist[t * 4 + 0], c1 = hist[t * 4 + 1];
        unsigned c2 = hist[t * 4 + 2], c3 = hist[t * 4 + 3];
        unsigned lsum = c0 + c1 + c2 + c3;
        unsigned incl = lsum;
#pragma unroll
        for (int off = 1; off < 64; off <<= 1) {
            unsigned n = __shfl_up(incl, off);
            if (t >= off) incl += n;
        }
        unsigned run = incl - lsum;
        if (run < NK && run + c0 >= NK) s_cut = t * 4 + 0;
        run += c0;
        if (run < NK && run + c1 >= NK) s_cut = t * 4 + 1;
        run += c1;
        if (run < NK && run + c2 >= NK) s_cut = t * 4 + 2;
        run += c2;
        if (run < NK && run + c3 >= NK) s_cut = t * 4 + 3;
    }
    __syncthreads();

    const int cut = s_cut;
    for (int j = 0; j < KJ; ++j) {
        int i = t + j * KT;
        float d = sdist[i];
        if ((int)(__float_as_uint(d) >> 23) <= cut) {
            unsigned p = atomicAdd(&ccnt, 1u);
            if (p < MAXC) { cd[p] = d; ci[p] = i; }
        }
    }
    __syncthreads();

    // one wave extracts the 16 smallest by (dist, idx)
    if (t < 64) {
        int cnt = (int)(ccnt < (unsigned)MAXC ? ccnt : (unsigned)MAXC);
        for (int r = 0; r < NK; ++r) {
            float bd = 3.4e38f; int bi = 0x7fffffff;
            for (int p = t; p < cnt; p += 64) {
                float d = cd[p]; int idx = ci[p];
                if (d < bd || (d == bd && idx < bi)) { bd = d; bi = idx; }
            }
#pragma unroll
            for (int off = 32; off >= 1; off >>= 1) {
                float od = __shfl_xor(bd, off);
                int   oi = __shfl_xor(bi, off);
                if (od < bd || (od == bd && oi < bi)) { bd = od; bi = oi; }
            }
            if (t == 0) knn[(size_t)q * NK + r] = bi;
            // invalidate winner (each lane touches only its own slots -> ordered)
            for (int p = t; p < cnt; p += 64) {
                if (ci[p] == bi) cd[p] = 3.4e38f;
            }
        }
    }
}

// ---------------- K4: gather precomputed h + max-pool ----------------
__global__ __launch_bounds__(128)
void gather_max_kernel(const float* __restrict__ h, const int* __restrict__ knn,
                       float* __restrict__ outF)
{
    const int q = blockIdx.x, o = threadIdx.x, b = q >> 11;
    __shared__ int sidx[NK];
    if (o < NK) sidx[o] = knn[(size_t)q * NK + o];
    __syncthreads();
    float m = -3.4e38f;
#pragma unroll
    for (int n = 0; n < NK; ++n) {
        float v = h[((size_t)b * NP + sidx[n]) * DOUT + o];
        m = fmaxf(m, v);
    }
    outF[(size_t)q * DOUT + o] = m;
}

// ---------------- K4': fallback if ws too small — fused gather + MLP + max ----------------
__global__ __launch_bounds__(128)
void fused_gather_mlp_kernel(const float* __restrict__ feat, const float* __restrict__ Wt,
                             const float* __restrict__ Cb, const int* __restrict__ knn,
                             float* __restrict__ outF)
{
    const int q = blockIdx.x, o = threadIdx.x, b = q >> 11;
    __shared__ int sidx[NK];
    __shared__ float sf[NK][DIN];
    if (o < NK) sidx[o] = knn[(size_t)q * NK + o];
    __syncthreads();
    for (int j = o; j < NK * DIN; j += 128) {
        int n = j >> 6;
        sf[n][j & 63] = feat[((size_t)b * NP + sidx[n]) * DIN + (j & 63)];
    }
    __syncthreads();
    const float cb0 = Cb[o];
    float m = -3.4e38f;
    for (int n = 0; n < NK; ++n) {
        float acc = cb0;
        const float4* f4 = (const float4*)sf[n];
#pragma unroll
        for (int k4 = 0; k4 < DIN / 4; ++k4) {
            float4 f = f4[k4];
            acc = fmaf(f.x, Wt[(k4 * 4 + 0) * DOUT + o], acc);
            acc = fmaf(f.y, Wt[(k4 * 4 + 1) * DOUT + o], acc);
            acc = fmaf(f.z, Wt[(k4 * 4 + 2) * DOUT + o], acc);
            acc = fmaf(f.w, Wt[(k4 * 4 + 3) * DOUT + o], acc);
        }
        m = fmaxf(m, fmaxf(acc, 0.0f));
    }
    outF[(size_t)q * DOUT + o] = m;
}

extern "C" void kernel_launch(void* const* d_in, const int* in_sizes, int n_in,
                              void* d_out, int out_size, void* d_ws, size_t ws_size,
                              hipStream_t stream)
{
    const float* coords = (const float*)d_in[0];
    const float* feat   = (const float*)d_in[1];
    const float* W      = (const float*)d_in[2];
    const float* bias   = (const float*)d_in[3];
    const float* gamma  = (const float*)d_in[4];
    const float* beta   = (const float*)d_in[5];
    const float* rmean  = (const float*)d_in[6];
    const float* rvar   = (const float*)d_in[7];

    float* out_coords = (float*)d_out;                    // [8,2048,3]
    float* out_feat   = out_coords + (size_t)NB * NS * 3; // [8,2048,128]

    char* ws = (char*)d_ws;
    float* Wt = (float*)ws;                                   // 32 KB
    float* Cb = (float*)(ws + 32768);                         // 512 B
    int*   knn = (int*)(ws + 65536);                          // 1 MB
    size_t knn_bytes = (size_t)NB * NS * NK * 4;
    float* h = (float*)(ws + 65536 + knn_bytes);              // 33.5 MB
    size_t need_h = (size_t)NB * NP * DOUT * 4;
    bool pathA = ws_size >= 65536 + knn_bytes + need_h;

    fold_weights_kernel<<<(DIN * DOUT + 255) / 256, 256, 0, stream>>>(
        W, bias, gamma, beta, rmean, rvar, Wt, Cb);
    if (pathA)
        mlp_kernel<<<NB * NP / 2, 256, 0, stream>>>(feat, Wt, Cb, h);
    fps_kernel<<<NB, FT, 0, stream>>>(coords, out_coords);
    knn_kernel<<<NB * NS, KT, 0, stream>>>(coords, out_coords, knn);
    if (pathA)
        gather_max_kernel<<<NB * NS, 128, 0, stream>>>(h, knn, out_feat);
    else
        fused_gather_mlp_kernel<<<NB * NS, 128, 0, stream>>>(feat, Wt, Cb, knn, out_feat);
}